// Round 11
// baseline (416.308 us; speedup 1.0000x reference)
//
#include <hip/hip_runtime.h>
#include <hip/hip_bf16.h>
#include <stdint.h>

// Problem constants
#define B_   64
#define T_   300
#define NIN  2312
#define H1   512
#define H2   256
#define NOUT 101
#define KP   2368   // NIN padded to multiple of 64
#define NT   (KP / 64)
#define CH   15     // I1 staging chunk (timesteps); 300 = 20*15
#define NC   (T_ / CH)

typedef __attribute__((ext_vector_type(8))) short bf16x8;
typedef __attribute__((ext_vector_type(4))) float f32x4;
typedef __attribute__((ext_vector_type(8))) unsigned short u16x8;
typedef __attribute__((ext_vector_type(4))) unsigned int u32x4;

#define LDS_GLOAD16(g, l) \
  __builtin_amdgcn_global_load_lds((const __attribute__((address_space(1))) void*)(g), \
                                   (__attribute__((address_space(3))) void*)(l), 16, 0, 0)

// ---------------- transpose helper ----------------
__global__ void transpose_k(const float* __restrict__ src, float* __restrict__ dst,
                            int R, int C) {
    int idx = blockIdx.x * 256 + threadIdx.x;
    if (idx < R * C) {
        int r = idx / C, c = idx % C;
        dst[c * R + r] = src[r * C + c];
    }
}

// ---------------- fp32 -> bf16 (RNE) with K-padding (W only) ----------------
__device__ __forceinline__ unsigned short rne_bf16(float v) {
    union { float f; unsigned u; } cv; cv.f = v;
    return (unsigned short)((cv.u + 0x7fff + ((cv.u >> 16) & 1)) >> 16);
}

__global__ __launch_bounds__(256) void cvt_pad_bf16(const float* __restrict__ src,
                                                    unsigned short* __restrict__ dst,
                                                    int R, int C, int Cp) {
    int idx = blockIdx.x * 256 + threadIdx.x;
    int cpw = Cp >> 3;
    if (idx >= R * cpw) return;
    int row = idx / cpw;
    int c0 = (idx - row * cpw) << 3;
    u16x8 o;
#pragma unroll
    for (int j = 0; j < 8; ++j) {
        int k = c0 + j;
        o[j] = (k < C) ? rne_bf16(src[(size_t)row * C + k]) : (unsigned short)0;
    }
    *(u16x8*)(dst + (size_t)row * Cp + c0) = o;
}

// ---- barrier-free 1-wave GEMM: Y[M][H1] = bf16(X) * Wb^T ----
// Tile 32(M) x 128(N): grid 600x4 = 2400 one-wave blocks. Each block reads its
// A rows ONCE (fp32->reg->cvt_pk_bf16), B fragments load direct from L2-resident
// Wb (2.4 MB, fits per-XCD L2) to registers. No LDS, no barriers: waves fully
// independent; TLP hides L2 latency. Fixes R10's 710 MB A-re-read-through-L3.
__device__ __forceinline__ unsigned cvt_pk(float lo, float hi) {
    unsigned r;
    asm("v_cvt_pk_bf16_f32 %0, %1, %2" : "=v"(r) : "v"(lo), "v"(hi));
    return r;
}

__global__ __launch_bounds__(64) void gemm_wave(
    const float* __restrict__ X,             // [M][NIN] fp32
    const unsigned short* __restrict__ Wb,   // [H1][KP] bf16 bits
    float* __restrict__ Y)                   // [M][H1]
{
    const int lane = threadIdx.x;
    // XCD swizzle: hw id d -> work wg so the 4 n-blocks of an m-panel share an
    // XCD (A-panel L2 reuse). 2400 % 8 == 0, 300 % 4 == 0 -> no panel splits.
    const int d  = blockIdx.x + gridDim.x * blockIdx.y;   // 0..2399
    const int wg = (d & 7) * 300 + (d >> 3);
    const int bn = wg & 3, bm = wg >> 2;
    const int m0 = bm * 32, n0 = bn * 128;
    const int fr = lane & 15, fq = lane >> 4;

    f32x4 acc[2][8] = {};   // [mi][nj]

    const float* gA0 = X + (size_t)(m0 + fr) * NIN;        // mi = 0 row
    const float* gA1 = X + (size_t)(m0 + 16 + fr) * NIN;   // mi = 1 row
    const unsigned short* gBr = Wb + (size_t)(n0 + fr) * KP;

    for (int kt = 0; kt < NT; ++kt) {
        const int kb = kt * 64;

        // ---- A: 8 x float4 fp32 loads (guard only in last kt; NIN % 8 == 0) ----
        float4 av[2][2][2];   // [mi][ks][half]
        if (kt + 1 < NT) {
#pragma unroll
            for (int mi = 0; mi < 2; ++mi)
#pragma unroll
                for (int ks = 0; ks < 2; ++ks) {
                    const float* p = (mi ? gA1 : gA0) + kb + ks * 32 + fq * 8;
                    av[mi][ks][0] = *(const float4*)p;
                    av[mi][ks][1] = *(const float4*)(p + 4);
                }
        } else {
#pragma unroll
            for (int mi = 0; mi < 2; ++mi)
#pragma unroll
                for (int ks = 0; ks < 2; ++ks) {
                    const int col0 = kb + ks * 32 + fq * 8;
                    const float* p = (mi ? gA1 : gA0) + col0;
                    av[mi][ks][0] = (col0 + 4 <= NIN) ? *(const float4*)p
                                                      : make_float4(0.f, 0.f, 0.f, 0.f);
                    av[mi][ks][1] = (col0 + 8 <= NIN) ? *(const float4*)(p + 4)
                                                      : make_float4(0.f, 0.f, 0.f, 0.f);
                }
        }

        // ---- B: 16 x 16B loads direct to regs (Wb zero-padded to KP) ----
        u32x4 bv[8][2];   // [nj][ks]
#pragma unroll
        for (int nj = 0; nj < 8; ++nj)
#pragma unroll
            for (int ks = 0; ks < 2; ++ks)
                bv[nj][ks] = *(const u32x4*)(gBr + (size_t)nj * 16 * KP + kb + ks * 32 + fq * 8);

        // ---- cvt A to bf16 fragments (v_cvt_pk_bf16_f32: 2 floats/inst) ----
        bf16x8 af[2][2];
#pragma unroll
        for (int mi = 0; mi < 2; ++mi)
#pragma unroll
            for (int ks = 0; ks < 2; ++ks) {
                u32x4 u;
                u.x = cvt_pk(av[mi][ks][0].x, av[mi][ks][0].y);
                u.y = cvt_pk(av[mi][ks][0].z, av[mi][ks][0].w);
                u.z = cvt_pk(av[mi][ks][1].x, av[mi][ks][1].y);
                u.w = cvt_pk(av[mi][ks][1].z, av[mi][ks][1].w);
                af[mi][ks] = __builtin_bit_cast(bf16x8, u);
            }

        // ---- MFMA: 2 ks x 8 nj x 2 mi = 32 per kt ----
#pragma unroll
        for (int ks = 0; ks < 2; ++ks)
#pragma unroll
            for (int nj = 0; nj < 8; ++nj) {
                bf16x8 b = __builtin_bit_cast(bf16x8, bv[nj][ks]);
#pragma unroll
                for (int mi = 0; mi < 2; ++mi)
                    acc[mi][nj] = __builtin_amdgcn_mfma_f32_16x16x32_bf16(
                        af[mi][ks], b, acc[mi][nj], 0, 0, 0);
            }
    }

    // C/D layout (m89-verified): col = lane&15, row = (lane>>4)*4 + reg
#pragma unroll
    for (int mi = 0; mi < 2; ++mi)
#pragma unroll
        for (int nj = 0; nj < 8; ++nj) {
            int r0 = m0 + mi * 16 + fq * 4;
            int c  = n0 + nj * 16 + fr;
#pragma unroll
            for (int r = 0; r < 4; ++r)
                Y[(size_t)(r0 + r) * H1 + c] = acc[mi][nj][r];
        }
}

// ---------------- wave-per-batch SNN scan (v6, unchanged) ----------------
__global__ __launch_bounds__(64) void snn_scan_wave(
    const float* __restrict__ I1ff,   // [B][T][H1]
    const float* __restrict__ wrt,    // [H1][H1]  wrt[i][h] = w_rec[h][i]
    const float* __restrict__ w2t,    // [H1][H2]  w2t[i][g] = w2[g][i]
    const float* __restrict__ w3t,    // [H2][NOUT]
    const float* __restrict__ alpha1, const float* __restrict__ rho1,
    const float* __restrict__ beta_a1,
    const float* __restrict__ alpha2, const float* __restrict__ rho2,
    const float* __restrict__ beta_a2,
    const float* __restrict__ beta_out,
    float* __restrict__ out)          // [B][NOUT]
{
    __shared__ __align__(16) float Ich[2][CH][H1];   // 60 KB

    const int b = blockIdx.x;
    const int lane = threadIdx.x;     // 0..63

    float v1[8], a1[8], s1f[8], al1[8], oml1[8], rh1[8], ba1[8];
#pragma unroll
    for (int j = 0; j < 8; ++j) {
        int h = lane + 64 * j;
        v1[j] = 0.f; a1[j] = 0.f; s1f[j] = 0.f;
        al1[j] = alpha1[h]; oml1[j] = 1.f - al1[j];
        rh1[j] = rho1[h];   ba1[j] = beta_a1[h];
    }
    float v2[4], a2[4], s2f[4], al2[4], oml2[4], rh2[4], ba2[4];
#pragma unroll
    for (int j = 0; j < 4; ++j) {
        int h = lane + 64 * j;
        v2[j] = 0.f; a2[j] = 0.f; s2f[j] = 0.f;
        al2[j] = alpha2[h]; oml2[j] = 1.f - al2[j];
        rh2[j] = rho2[h];   ba2[j] = beta_a2[h];
    }
    float vo0 = 0.f, vo1 = 0.f, vs0 = 0.f, vs1 = 0.f;
    const float bo0 = beta_out[lane];
    const float ombo0 = 1.f - bo0;
    const float bo1 = (lane < NOUT - 64) ? beta_out[64 + lane] : 0.f;
    const float ombo1 = 1.f - bo1;

    unsigned long long M1[8];
#pragma unroll
    for (int j = 0; j < 8; ++j) M1[j] = 0ull;
    bool prev1 = false;

    const float* I1p = I1ff + (size_t)b * T_ * H1;

    auto stage = [&](int c, int bufi) {
        const float* src = I1p + (size_t)c * CH * H1 + lane * 4;
#pragma unroll
        for (int s = 0; s < CH; ++s) {
            LDS_GLOAD16(src + (size_t)s * H1,       &Ich[bufi][s][0]);
            LDS_GLOAD16(src + (size_t)s * H1 + 256, &Ich[bufi][s][256]);
        }
    };

    stage(0, 0);

    for (int c = 0; c < NC; ++c) {
        const int buf = c & 1;
        asm volatile("s_waitcnt vmcnt(0)" ::: "memory");

        float cur[8];
#pragma unroll
        for (int j = 0; j < 8; ++j) cur[j] = Ich[buf][0][lane + 64 * j];

        for (int s = 0; s < CH; ++s) {
            float nxt[8];
            if (s + 1 < CH) {
#pragma unroll
                for (int j = 0; j < 8; ++j) nxt[j] = Ich[buf][s + 1][lane + 64 * j];
            }

            float rec[8] = {0.f,0.f,0.f,0.f,0.f,0.f,0.f,0.f};
            if (prev1) {
#pragma unroll
                for (int w = 0; w < 8; ++w) {
                    unsigned long long bits = M1[w];
                    while (bits) {
                        int p = __builtin_ctzll(bits);
                        bits &= bits - 1;
                        int i = (w << 6) + p;
                        const float* r = wrt + (size_t)i * H1 + lane;
#pragma unroll
                        for (int j = 0; j < 8; ++j) rec[j] += r[64 * j];
                    }
                }
            }

            unsigned m = 0;
#pragma unroll
            for (int j = 0; j < 8; ++j) {
                float I1v = cur[j] + rec[j];
                float v1n = fmaf(al1[j], v1[j], oml1[j] * (I1v - a1[j]));
                bool  sp  = v1n > 1.f;
                v1[j] = sp ? v1n - 1.f : v1n;
                a1[j] = fmaf(rh1[j], a1[j], ba1[j] * s1f[j]);
                s1f[j] = sp ? 1.f : 0.f;
                m |= (sp ? 1u : 0u) << j;
            }

            unsigned long long anyb = __ballot(m != 0);
            float I2[4] = {0.f, 0.f, 0.f, 0.f};
            if (anyb) {
                prev1 = true;
#pragma unroll
                for (int j = 0; j < 8; ++j) M1[j] = __ballot((m >> j) & 1);
#pragma unroll
                for (int w = 0; w < 8; ++w) {
                    unsigned long long bits = M1[w];
                    while (bits) {
                        int p = __builtin_ctzll(bits);
                        bits &= bits - 1;
                        int i = (w << 6) + p;
                        const float* r = w2t + (size_t)i * H2 + lane;
#pragma unroll
                        for (int j = 0; j < 4; ++j) I2[j] += r[64 * j];
                    }
                }
            } else {
                prev1 = false;
            }

            unsigned m2 = 0;
#pragma unroll
            for (int j = 0; j < 4; ++j) {
                float v2n = fmaf(al2[j], v2[j], oml2[j] * (I2[j] - a2[j]));
                bool  sp  = v2n > 1.f;
                v2[j] = sp ? v2n - 1.f : v2n;
                a2[j] = fmaf(rh2[j], a2[j], ba2[j] * s2f[j]);
                s2f[j] = sp ? 1.f : 0.f;
                m2 |= (sp ? 1u : 0u) << j;
            }

            unsigned long long any2 = __ballot(m2 != 0);
            float io0 = 0.f, io1 = 0.f;
            if (any2) {
#pragma unroll
                for (int w = 0; w < 4; ++w) {
                    unsigned long long bits = __ballot((m2 >> w) & 1);
                    while (bits) {
                        int p = __builtin_ctzll(bits);
                        bits &= bits - 1;
                        int i = (w << 6) + p;
                        io0 += w3t[(size_t)i * NOUT + lane];
                        if (lane < NOUT - 64) io1 += w3t[(size_t)i * NOUT + 64 + lane];
                    }
                }
            }
            vo0 = fmaf(bo0, vo0, ombo0 * io0);
            vo1 = fmaf(bo1, vo1, ombo1 * io1);
            vs0 += vo0;
            vs1 += vo1;

#pragma unroll
            for (int j = 0; j < 8; ++j) cur[j] = nxt[j];
        }

        if (c + 1 < NC) stage(c + 1, buf ^ 1);
    }

    out[b * NOUT + lane] = vs0 * (1.f / (float)T_);
    if (lane < NOUT - 64) out[b * NOUT + 64 + lane] = vs1 * (1.f / (float)T_);
}

// ---------------- launch ----------------
extern "C" void kernel_launch(void* const* d_in, const int* in_sizes, int n_in,
                              void* d_out, int out_size, void* d_ws, size_t ws_size,
                              hipStream_t stream) {
    const float* x      = (const float*)d_in[0];   // [B][T][NIN]
    const float* w1     = (const float*)d_in[1];   // [H1][NIN]
    const float* w_rec  = (const float*)d_in[2];   // [H1][H1]
    const float* w2     = (const float*)d_in[3];   // [H2][H1]
    const float* w3     = (const float*)d_in[4];   // [NOUT][H2]
    const float* alpha1 = (const float*)d_in[5];
    const float* rho1   = (const float*)d_in[6];
    const float* beta_a1= (const float*)d_in[7];
    const float* alpha2 = (const float*)d_in[8];
    const float* rho2   = (const float*)d_in[9];
    const float* beta_a2= (const float*)d_in[10];
    const float* beta_out=(const float*)d_in[11];
    float* out = (float*)d_out;

    const int M = B_ * T_;                         // 19200

    size_t off = 0;
    auto take = [&](size_t bytes) {
        void* p = (char*)d_ws + off;
        off += (bytes + 255) & ~(size_t)255;
        return p;
    };
    float* I1ff = (float*)take((size_t)M * H1 * 4);            // 39.3 MB
    float* wrt  = (float*)take((size_t)H1 * H1 * 4);
    float* w2t  = (float*)take((size_t)H1 * H2 * 4);
    float* w3t  = (float*)take((size_t)H2 * NOUT * 4);
    unsigned short* w1b = (unsigned short*)take((size_t)H1 * KP * 2);  // 2.4 MB

    transpose_k<<<(H1 * H1 + 255) / 256, 256, 0, stream>>>(w_rec, wrt, H1, H1);
    transpose_k<<<(H2 * H1 + 255) / 256, 256, 0, stream>>>(w2, w2t, H2, H1);
    transpose_k<<<(NOUT * H2 + 255) / 256, 256, 0, stream>>>(w3, w3t, NOUT, H2);

    // W -> bf16 (tiny, zero-padded to KP); A converts in-GEMM
    int nw = H1 * (KP / 8);
    cvt_pad_bf16<<<(nw + 255) / 256, 256, 0, stream>>>(w1, w1b, H1, NIN, KP);

    // barrier-free 1-wave GEMM: grid (4, 600) = 2400 blocks of 64 threads
    dim3 gg(H1 / 128, M / 32);
    gemm_wave<<<gg, 64, 0, stream>>>(x, w1b, I1ff);

    snn_scan_wave<<<B_, 64, 0, stream>>>(I1ff, wrt, w2t, w3t,
                                         alpha1, rho1, beta_a1,
                                         alpha2, rho2, beta_a2,
                                         beta_out, out);
}

// Round 12
// 267.314 us; speedup vs baseline: 1.5574x; 1.5574x over previous
//
#include <hip/hip_runtime.h>
#include <hip/hip_bf16.h>
#include <stdint.h>

// Problem constants
#define B_   64
#define T_   300
#define NIN  2312
#define H1   512
#define H2   256
#define NOUT 101
#define KP   2368   // NIN padded to multiple of 64
#define NT   (KP / 64)
#define CH   15     // I1 staging chunk (timesteps); 300 = 20*15
#define NC   (T_ / CH)

typedef __attribute__((ext_vector_type(8))) short bf16x8;
typedef __attribute__((ext_vector_type(4))) float f32x4;
typedef __attribute__((ext_vector_type(8))) unsigned short u16x8;

#define LDS_GLOAD16(g, l) \
  __builtin_amdgcn_global_load_lds((const __attribute__((address_space(1))) void*)(g), \
                                   (__attribute__((address_space(3))) void*)(l), 16, 0, 0)
#define CFENCE() asm volatile("" ::: "memory")

// ---------------- transpose helper ----------------
__global__ void transpose_k(const float* __restrict__ src, float* __restrict__ dst,
                            int R, int C) {
    int idx = blockIdx.x * 256 + threadIdx.x;
    if (idx < R * C) {
        int r = idx / C, c = idx % C;
        dst[c * R + r] = src[r * C + c];
    }
}

// ---------------- fp32 -> bf16 (RNE) with K-padding (W only) ----------------
__device__ __forceinline__ unsigned short rne_bf16(float v) {
    union { float f; unsigned u; } cv; cv.f = v;
    return (unsigned short)((cv.u + 0x7fff + ((cv.u >> 16) & 1)) >> 16);
}

__global__ __launch_bounds__(256) void cvt_pad_bf16(const float* __restrict__ src,
                                                    unsigned short* __restrict__ dst,
                                                    int R, int C, int Cp) {
    int idx = blockIdx.x * 256 + threadIdx.x;
    int cpw = Cp >> 3;
    if (idx >= R * cpw) return;
    int row = idx / cpw;
    int c0 = (idx - row * cpw) << 3;
    u16x8 o;
#pragma unroll
    for (int j = 0; j < 8; ++j) {
        int k = c0 + j;
        o[j] = (k < C) ? rne_bf16(src[(size_t)row * C + k]) : (unsigned short)0;
    }
    *(u16x8*)(dst + (size_t)row * Cp + c0) = o;
}

// ------------- full-N GEMM: tile 32(M) x 512(N), A read exactly once ----------
// Y[M][H1] = bf16(X[M][NIN]) * Wb[H1][KP]^T.  Grid = 600 blocks x 256 threads.
// No n-splitting -> A panel read ONCE (fixes the 4x fp32 A re-read that bound
// R8/R10 at ~150us). B: whole Wb k-slab (512x64, 64KB) staged per kt via
// coalesced pre-swizzled global_load_lds (L2-resident, 2.4MB/XCD). A: reg-staged
// fp32 -> v_cvt_pk_bf16_f32 -> swizzled ds_write (4KB/kt). Wave w owns n-cols
// [128w, 128w+128). LDS 68KB -> 2 blocks/CU (= grid's 2.34/CU).
__device__ __forceinline__ unsigned cvt_pk(float lo, float hi) {
    unsigned r;
    asm("v_cvt_pk_bf16_f32 %0, %1, %2" : "=v"(r) : "v"(lo), "v"(hi));
    return r;
}

__global__ __launch_bounds__(256) void gemm_fullN(
    const float* __restrict__ X,             // [M][NIN] fp32
    const unsigned short* __restrict__ Wb,   // [H1][KP] bf16 bits
    float* __restrict__ Y)                   // [M][H1]
{
    __shared__ __align__(16) unsigned short As[32][64];    // 4 KB
    __shared__ __align__(16) unsigned short Bs[512][64];   // 64 KB

    const int tid  = threadIdx.x;
    const int wave = tid >> 6, lane = tid & 63;
    const int m0 = blockIdx.x * 32;
    const int fr = lane & 15, fq = lane >> 4;
    const int swz = (fr & 7) << 3;             // element XOR for reads
    const int n0w = wave * 128;                // this wave's n-range

    f32x4 acc[2][8] = {};                      // [mi][nj]

    // ---- A addressing: row = tid>>3 (0..31), col8 = (tid&7)*8 ----
    const int arow = tid >> 3, acol = (tid & 7) * 8;
    const float* gA = X + (size_t)(m0 + arow) * NIN + acol;
    unsigned short* lA = &As[arow][acol ^ ((arow & 7) << 3)];   // swizzled dest

    // ---- B addressing: wave stages rows [128w..128w+128), 16 instrs x 8 rows --
    const size_t rowBW = (size_t)KP * 2;
    const int bcolsw = 16 * ((lane & 7) ^ ((lane >> 3) & 7));   // pre-swizzled src
    const char* gB = (const char*)Wb + (size_t)(128 * wave + (lane >> 3)) * rowBW + bcolsw;
    unsigned short* lB = &Bs[128 * wave][0];

    float4 a0, a1;
    auto loadA = [&](int kt) {
        const int col0 = kt * 64 + acol;
        const float* p = gA + kt * 64;
        a0 = (col0 + 4 <= NIN) ? *(const float4*)p       : make_float4(0.f, 0.f, 0.f, 0.f);
        a1 = (col0 + 8 <= NIN) ? *(const float4*)(p + 4) : make_float4(0.f, 0.f, 0.f, 0.f);
    };

    loadA(0);   // prologue (A loads oldest in vmem FIFO)

    for (int kt = 0; kt < NT; ++kt) {
        // ---- stage B(kt): 16 coalesced gload_lds per wave ----
        const size_t ko = (size_t)kt * 128;
        CFENCE();
#pragma unroll
        for (int s = 0; s < 16; ++s)
            LDS_GLOAD16(gB + ko + (size_t)s * 8 * rowBW, lB + s * 8 * 64);
        CFENCE();

        // ---- A: cvt + swizzled ds_write (compiler waits A regs only: oldest) --
        {
            uint4 o;
            o.x = cvt_pk(a0.x, a0.y);
            o.y = cvt_pk(a0.z, a0.w);
            o.z = cvt_pk(a1.x, a1.y);
            o.w = cvt_pk(a1.z, a1.w);
            *(uint4*)lA = o;
        }
        CFENCE();

        // ---- prefetch A(kt+1) regs (stays in flight across MFMA wait) ----
        if (kt + 1 < NT) {
            loadA(kt + 1);
            CFENCE();
            asm volatile("s_waitcnt vmcnt(2)" ::: "memory");   // B landed; A(kt+1) flying
        } else {
            CFENCE();
            asm volatile("s_waitcnt vmcnt(0)" ::: "memory");
        }
        asm volatile("s_waitcnt lgkmcnt(0)" ::: "memory");     // A ds_write visible
        __builtin_amdgcn_s_barrier();

        // ---- MFMA: 2 ks x 2 mi x 8 nj = 32 per wave ----
#pragma unroll
        for (int ks = 0; ks < 2; ++ks) {
            bf16x8 a[2], b[8];
#pragma unroll
            for (int mi = 0; mi < 2; ++mi)
                a[mi] = *(const bf16x8*)&As[mi * 16 + fr][(ks * 32 + fq * 8) ^ swz];
#pragma unroll
            for (int nj = 0; nj < 8; ++nj)
                b[nj] = *(const bf16x8*)&Bs[n0w + nj * 16 + fr][(ks * 32 + fq * 8) ^ swz];
#pragma unroll
            for (int mi = 0; mi < 2; ++mi)
#pragma unroll
                for (int nj = 0; nj < 8; ++nj)
                    acc[mi][nj] = __builtin_amdgcn_mfma_f32_16x16x32_bf16(
                        a[mi], b[nj], acc[mi][nj], 0, 0, 0);
        }
        __builtin_amdgcn_s_barrier();   // all reads done before next kt's staging
    }

    // C/D layout (m89-verified): col = lane&15, row = (lane>>4)*4 + reg
#pragma unroll
    for (int mi = 0; mi < 2; ++mi)
#pragma unroll
        for (int nj = 0; nj < 8; ++nj) {
            int r0 = m0 + mi * 16 + fq * 4;
            int c  = n0w + nj * 16 + fr;
#pragma unroll
            for (int r = 0; r < 4; ++r)
                Y[(size_t)(r0 + r) * H1 + c] = acc[mi][nj][r];
        }
}

// ---------------- wave-per-batch SNN scan (v6, unchanged) ----------------
__global__ __launch_bounds__(64) void snn_scan_wave(
    const float* __restrict__ I1ff,   // [B][T][H1]
    const float* __restrict__ wrt,    // [H1][H1]  wrt[i][h] = w_rec[h][i]
    const float* __restrict__ w2t,    // [H1][H2]  w2t[i][g] = w2[g][i]
    const float* __restrict__ w3t,    // [H2][NOUT]
    const float* __restrict__ alpha1, const float* __restrict__ rho1,
    const float* __restrict__ beta_a1,
    const float* __restrict__ alpha2, const float* __restrict__ rho2,
    const float* __restrict__ beta_a2,
    const float* __restrict__ beta_out,
    float* __restrict__ out)          // [B][NOUT]
{
    __shared__ __align__(16) float Ich[2][CH][H1];   // 60 KB

    const int b = blockIdx.x;
    const int lane = threadIdx.x;     // 0..63

    float v1[8], a1[8], s1f[8], al1[8], oml1[8], rh1[8], ba1[8];
#pragma unroll
    for (int j = 0; j < 8; ++j) {
        int h = lane + 64 * j;
        v1[j] = 0.f; a1[j] = 0.f; s1f[j] = 0.f;
        al1[j] = alpha1[h]; oml1[j] = 1.f - al1[j];
        rh1[j] = rho1[h];   ba1[j] = beta_a1[h];
    }
    float v2[4], a2[4], s2f[4], al2[4], oml2[4], rh2[4], ba2[4];
#pragma unroll
    for (int j = 0; j < 4; ++j) {
        int h = lane + 64 * j;
        v2[j] = 0.f; a2[j] = 0.f; s2f[j] = 0.f;
        al2[j] = alpha2[h]; oml2[j] = 1.f - al2[j];
        rh2[j] = rho2[h];   ba2[j] = beta_a2[h];
    }
    float vo0 = 0.f, vo1 = 0.f, vs0 = 0.f, vs1 = 0.f;
    const float bo0 = beta_out[lane];
    const float ombo0 = 1.f - bo0;
    const float bo1 = (lane < NOUT - 64) ? beta_out[64 + lane] : 0.f;
    const float ombo1 = 1.f - bo1;

    unsigned long long M1[8];
#pragma unroll
    for (int j = 0; j < 8; ++j) M1[j] = 0ull;
    bool prev1 = false;

    const float* I1p = I1ff + (size_t)b * T_ * H1;

    auto stage = [&](int c, int bufi) {
        const float* src = I1p + (size_t)c * CH * H1 + lane * 4;
#pragma unroll
        for (int s = 0; s < CH; ++s) {
            LDS_GLOAD16(src + (size_t)s * H1,       &Ich[bufi][s][0]);
            LDS_GLOAD16(src + (size_t)s * H1 + 256, &Ich[bufi][s][256]);
        }
    };

    stage(0, 0);

    for (int c = 0; c < NC; ++c) {
        const int buf = c & 1;
        asm volatile("s_waitcnt vmcnt(0)" ::: "memory");

        float cur[8];
#pragma unroll
        for (int j = 0; j < 8; ++j) cur[j] = Ich[buf][0][lane + 64 * j];

        for (int s = 0; s < CH; ++s) {
            float nxt[8];
            if (s + 1 < CH) {
#pragma unroll
                for (int j = 0; j < 8; ++j) nxt[j] = Ich[buf][s + 1][lane + 64 * j];
            }

            float rec[8] = {0.f,0.f,0.f,0.f,0.f,0.f,0.f,0.f};
            if (prev1) {
#pragma unroll
                for (int w = 0; w < 8; ++w) {
                    unsigned long long bits = M1[w];
                    while (bits) {
                        int p = __builtin_ctzll(bits);
                        bits &= bits - 1;
                        int i = (w << 6) + p;
                        const float* r = wrt + (size_t)i * H1 + lane;
#pragma unroll
                        for (int j = 0; j < 8; ++j) rec[j] += r[64 * j];
                    }
                }
            }

            unsigned m = 0;
#pragma unroll
            for (int j = 0; j < 8; ++j) {
                float I1v = cur[j] + rec[j];
                float v1n = fmaf(al1[j], v1[j], oml1[j] * (I1v - a1[j]));
                bool  sp  = v1n > 1.f;
                v1[j] = sp ? v1n - 1.f : v1n;
                a1[j] = fmaf(rh1[j], a1[j], ba1[j] * s1f[j]);
                s1f[j] = sp ? 1.f : 0.f;
                m |= (sp ? 1u : 0u) << j;
            }

            unsigned long long anyb = __ballot(m != 0);
            float I2[4] = {0.f, 0.f, 0.f, 0.f};
            if (anyb) {
                prev1 = true;
#pragma unroll
                for (int j = 0; j < 8; ++j) M1[j] = __ballot((m >> j) & 1);
#pragma unroll
                for (int w = 0; w < 8; ++w) {
                    unsigned long long bits = M1[w];
                    while (bits) {
                        int p = __builtin_ctzll(bits);
                        bits &= bits - 1;
                        int i = (w << 6) + p;
                        const float* r = w2t + (size_t)i * H2 + lane;
#pragma unroll
                        for (int j = 0; j < 4; ++j) I2[j] += r[64 * j];
                    }
                }
            } else {
                prev1 = false;
            }

            unsigned m2 = 0;
#pragma unroll
            for (int j = 0; j < 4; ++j) {
                float v2n = fmaf(al2[j], v2[j], oml2[j] * (I2[j] - a2[j]));
                bool  sp  = v2n > 1.f;
                v2[j] = sp ? v2n - 1.f : v2n;
                a2[j] = fmaf(rh2[j], a2[j], ba2[j] * s2f[j]);
                s2f[j] = sp ? 1.f : 0.f;
                m2 |= (sp ? 1u : 0u) << j;
            }

            unsigned long long any2 = __ballot(m2 != 0);
            float io0 = 0.f, io1 = 0.f;
            if (any2) {
#pragma unroll
                for (int w = 0; w < 4; ++w) {
                    unsigned long long bits = __ballot((m2 >> w) & 1);
                    while (bits) {
                        int p = __builtin_ctzll(bits);
                        bits &= bits - 1;
                        int i = (w << 6) + p;
                        io0 += w3t[(size_t)i * NOUT + lane];
                        if (lane < NOUT - 64) io1 += w3t[(size_t)i * NOUT + 64 + lane];
                    }
                }
            }
            vo0 = fmaf(bo0, vo0, ombo0 * io0);
            vo1 = fmaf(bo1, vo1, ombo1 * io1);
            vs0 += vo0;
            vs1 += vo1;

#pragma unroll
            for (int j = 0; j < 8; ++j) cur[j] = nxt[j];
        }

        if (c + 1 < NC) stage(c + 1, buf ^ 1);
    }

    out[b * NOUT + lane] = vs0 * (1.f / (float)T_);
    if (lane < NOUT - 64) out[b * NOUT + 64 + lane] = vs1 * (1.f / (float)T_);
}

// ---------------- launch ----------------
extern "C" void kernel_launch(void* const* d_in, const int* in_sizes, int n_in,
                              void* d_out, int out_size, void* d_ws, size_t ws_size,
                              hipStream_t stream) {
    const float* x      = (const float*)d_in[0];   // [B][T][NIN]
    const float* w1     = (const float*)d_in[1];   // [H1][NIN]
    const float* w_rec  = (const float*)d_in[2];   // [H1][H1]
    const float* w2     = (const float*)d_in[3];   // [H2][H1]
    const float* w3     = (const float*)d_in[4];   // [NOUT][H2]
    const float* alpha1 = (const float*)d_in[5];
    const float* rho1   = (const float*)d_in[6];
    const float* beta_a1= (const float*)d_in[7];
    const float* alpha2 = (const float*)d_in[8];
    const float* rho2   = (const float*)d_in[9];
    const float* beta_a2= (const float*)d_in[10];
    const float* beta_out=(const float*)d_in[11];
    float* out = (float*)d_out;

    const int M = B_ * T_;                         // 19200

    size_t off = 0;
    auto take = [&](size_t bytes) {
        void* p = (char*)d_ws + off;
        off += (bytes + 255) & ~(size_t)255;
        return p;
    };
    float* I1ff = (float*)take((size_t)M * H1 * 4);            // 39.3 MB
    float* wrt  = (float*)take((size_t)H1 * H1 * 4);
    float* w2t  = (float*)take((size_t)H1 * H2 * 4);
    float* w3t  = (float*)take((size_t)H2 * NOUT * 4);
    unsigned short* w1b = (unsigned short*)take((size_t)H1 * KP * 2);  // 2.4 MB

    transpose_k<<<(H1 * H1 + 255) / 256, 256, 0, stream>>>(w_rec, wrt, H1, H1);
    transpose_k<<<(H2 * H1 + 255) / 256, 256, 0, stream>>>(w2, w2t, H2, H1);
    transpose_k<<<(NOUT * H2 + 255) / 256, 256, 0, stream>>>(w3, w3t, NOUT, H2);

    // W -> bf16 (tiny, zero-padded to KP); A converts in-GEMM
    int nw = H1 * (KP / 8);
    cvt_pad_bf16<<<(nw + 255) / 256, 256, 0, stream>>>(w1, w1b, H1, NIN, KP);

    // full-N GEMM: 600 blocks x 256 threads, A read exactly once
    gemm_fullN<<<M / 32, 256, 0, stream>>>(x, w1b, I1ff);

    snn_scan_wave<<<B_, 64, 0, stream>>>(I1ff, wrt, w2t, w3t,
                                         alpha1, rho1, beta_a1,
                                         alpha2, rho2, beta_a2,
                                         beta_out, out);
}

// Round 13
// 231.672 us; speedup vs baseline: 1.7970x; 1.1538x over previous
//
#include <hip/hip_runtime.h>
#include <hip/hip_bf16.h>
#include <stdint.h>

// Problem constants
#define B_   64
#define T_   300
#define NIN  2312
#define H1   512
#define H2   256
#define NOUT 101
#define KP   2368   // NIN padded to multiple of 64
#define NT   (KP / 64)
#define CH   15     // I1 staging chunk (timesteps); 300 = 20*15
#define NC   (T_ / CH)

typedef __attribute__((ext_vector_type(8))) short bf16x8;
typedef __attribute__((ext_vector_type(4))) float f32x4;
typedef __attribute__((ext_vector_type(8))) unsigned short u16x8;

#define LDS_GLOAD16(g, l) \
  __builtin_amdgcn_global_load_lds((const __attribute__((address_space(1))) void*)(g), \
                                   (__attribute__((address_space(3))) void*)(l), 16, 0, 0)

// ---------------- transpose helper ----------------
__global__ void transpose_k(const float* __restrict__ src, float* __restrict__ dst,
                            int R, int C) {
    int idx = blockIdx.x * 256 + threadIdx.x;
    if (idx < R * C) {
        int r = idx / C, c = idx % C;
        dst[c * R + r] = src[r * C + c];
    }
}

// ---------------- fp32 -> bf16 (RNE) with K-padding, float4 loads ----------------
__device__ __forceinline__ unsigned short rne_bf16(float v) {
    union { float f; unsigned u; } cv; cv.f = v;
    return (unsigned short)((cv.u + 0x7fff + ((cv.u >> 16) & 1)) >> 16);
}

__global__ __launch_bounds__(256) void cvt_pad_bf16(const float* __restrict__ src,
                                                    unsigned short* __restrict__ dst,
                                                    int R, int C, int Cp) {
    int idx = blockIdx.x * 256 + threadIdx.x;
    int cpw = Cp >> 3;
    if (idx >= R * cpw) return;
    int row = idx / cpw;
    int c0 = (idx - row * cpw) << 3;
    u16x8 o;
    if (c0 + 8 <= C) {
        const float4* s = (const float4*)(src + (size_t)row * C + c0);
        float4 v0 = s[0], v1 = s[1];
        float v[8] = {v0.x, v0.y, v0.z, v0.w, v1.x, v1.y, v1.z, v1.w};
#pragma unroll
        for (int j = 0; j < 8; ++j) o[j] = rne_bf16(v[j]);
    } else {
#pragma unroll
        for (int j = 0; j < 8; ++j) {
            int k = c0 + j;
            o[j] = (k < C) ? rne_bf16(src[(size_t)row * C + k]) : (unsigned short)0;
        }
    }
    *(u16x8*)(dst + (size_t)row * Cp + c0) = o;
}

// ---- bf16 GEMM, 128(M) x 256(N) tile, both operands via global_load_lds ----
// Y[M][H1] = Xb[M][KP] * Wb[H1][KP]^T.  8 waves (512 thr), wave = 64x64 out.
// Per-block traffic: A 0.6MB + B 0.6MB bf16 (vs R8's 1.2MB fp32 A + 0.6 B);
// B re-read halved vs 128-wide tiles. Simple sync (compiler-inserted vmcnt):
// hand-rolled vmcnt schedules regressed twice (R9/R10). LDS XOR-swizzle on
// both operands via pre-swizzled per-lane source (R8-verified: conflicts 0).
__global__ __launch_bounds__(512) void gemm_bf16(
    const unsigned short* __restrict__ Xb,   // [M][KP] bf16 bits
    const unsigned short* __restrict__ Wb,   // [H1][KP] bf16 bits
    float* __restrict__ Y)                   // [M][H1]
{
    __shared__ __align__(16) unsigned short As[128][64];   // 16 KB
    __shared__ __align__(16) unsigned short Bs[256][64];   // 32 KB

    const int tid  = threadIdx.x;
    const int wave = tid >> 6, lane = tid & 63;
    const int wr = wave >> 2, wc = wave & 3;          // 2x4 waves, 64x64 each

    // m204 bijective XCD swizzle for 300 blocks (300 % 8 == 4)
    const int d  = blockIdx.x;                        // 0..299
    const int xcd = d & 7, i = d >> 3;
    const int q = 300 / 8, r = 300 % 8;               // 37, 4
    const int wg = (xcd < r) ? xcd * (q + 1) + i : r * (q + 1) + (xcd - r) * q + i;
    const int bn = wg & 1, bm = wg >> 1;
    const int m0 = bm * 128, n0 = bn * 256;
    const int fr = lane & 15, fq = lane >> 4;
    const int swz = (fr & 7) << 3;                    // element XOR for reads

    f32x4 acc[4][4] = {};

    // staging addressing: per instr, 64 lanes x 16B = 8 rows of 128B.
    // source col pre-swizzled so linear LDS dest yields swizzled layout.
    const size_t rowB = (size_t)KP * 2;
    const int colsw = 16 * ((lane & 7) ^ (lane >> 3));          // bytes
    // A: wave stages rows [16w .. 16w+16) (2 instrs)
    const char* gA = (const char*)Xb + (size_t)(m0 + 16 * wave + (lane >> 3)) * rowB + colsw;
    unsigned short* lA = &As[16 * wave][0];
    // B: wave stages rows [32w .. 32w+32) (4 instrs)
    const char* gB = (const char*)Wb + (size_t)(n0 + 32 * wave + (lane >> 3)) * rowB + colsw;
    unsigned short* lB = &Bs[32 * wave][0];

    for (int kt = 0; kt < NT; ++kt) {
        const size_t ko = (size_t)kt * 128;           // byte offset along K
#pragma unroll
        for (int s = 0; s < 2; ++s)
            LDS_GLOAD16(gA + ko + (size_t)s * 8 * rowB, lA + s * 8 * 64);
#pragma unroll
        for (int s = 0; s < 4; ++s)
            LDS_GLOAD16(gB + ko + (size_t)s * 8 * rowB, lB + s * 8 * 64);
        __syncthreads();   // compiler drains vmcnt before barrier

#pragma unroll
        for (int ks = 0; ks < 2; ++ks) {
            bf16x8 a[4], b[4];
#pragma unroll
            for (int mi = 0; mi < 4; ++mi)
                a[mi] = *(const bf16x8*)&As[wr * 64 + mi * 16 + fr][(ks * 32 + fq * 8) ^ swz];
#pragma unroll
            for (int nj = 0; nj < 4; ++nj)
                b[nj] = *(const bf16x8*)&Bs[wc * 64 + nj * 16 + fr][(ks * 32 + fq * 8) ^ swz];
#pragma unroll
            for (int mi = 0; mi < 4; ++mi)
#pragma unroll
                for (int nj = 0; nj < 4; ++nj)
                    acc[mi][nj] = __builtin_amdgcn_mfma_f32_16x16x32_bf16(
                        a[mi], b[nj], acc[mi][nj], 0, 0, 0);
        }
        __syncthreads();
    }

    // C/D layout (m89-verified): col = lane&15, row = (lane>>4)*4 + reg
#pragma unroll
    for (int mi = 0; mi < 4; ++mi)
#pragma unroll
        for (int nj = 0; nj < 4; ++nj) {
            int r0 = m0 + wr * 64 + mi * 16 + fq * 4;
            int c  = n0 + wc * 64 + nj * 16 + fr;
#pragma unroll
            for (int rr = 0; rr < 4; ++rr)
                Y[(size_t)(r0 + rr) * H1 + c] = acc[mi][nj][rr];
        }
}

// ---------------- wave-per-batch SNN scan (v6, unchanged) ----------------
__global__ __launch_bounds__(64) void snn_scan_wave(
    const float* __restrict__ I1ff,   // [B][T][H1]
    const float* __restrict__ wrt,    // [H1][H1]  wrt[i][h] = w_rec[h][i]
    const float* __restrict__ w2t,    // [H1][H2]  w2t[i][g] = w2[g][i]
    const float* __restrict__ w3t,    // [H2][NOUT]
    const float* __restrict__ alpha1, const float* __restrict__ rho1,
    const float* __restrict__ beta_a1,
    const float* __restrict__ alpha2, const float* __restrict__ rho2,
    const float* __restrict__ beta_a2,
    const float* __restrict__ beta_out,
    float* __restrict__ out)          // [B][NOUT]
{
    __shared__ __align__(16) float Ich[2][CH][H1];   // 60 KB

    const int b = blockIdx.x;
    const int lane = threadIdx.x;     // 0..63

    float v1[8], a1[8], s1f[8], al1[8], oml1[8], rh1[8], ba1[8];
#pragma unroll
    for (int j = 0; j < 8; ++j) {
        int h = lane + 64 * j;
        v1[j] = 0.f; a1[j] = 0.f; s1f[j] = 0.f;
        al1[j] = alpha1[h]; oml1[j] = 1.f - al1[j];
        rh1[j] = rho1[h];   ba1[j] = beta_a1[h];
    }
    float v2[4], a2[4], s2f[4], al2[4], oml2[4], rh2[4], ba2[4];
#pragma unroll
    for (int j = 0; j < 4; ++j) {
        int h = lane + 64 * j;
        v2[j] = 0.f; a2[j] = 0.f; s2f[j] = 0.f;
        al2[j] = alpha2[h]; oml2[j] = 1.f - al2[j];
        rh2[j] = rho2[h];   ba2[j] = beta_a2[h];
    }
    float vo0 = 0.f, vo1 = 0.f, vs0 = 0.f, vs1 = 0.f;
    const float bo0 = beta_out[lane];
    const float ombo0 = 1.f - bo0;
    const float bo1 = (lane < NOUT - 64) ? beta_out[64 + lane] : 0.f;
    const float ombo1 = 1.f - bo1;

    unsigned long long M1[8];
#pragma unroll
    for (int j = 0; j < 8; ++j) M1[j] = 0ull;
    bool prev1 = false;

    const float* I1p = I1ff + (size_t)b * T_ * H1;

    auto stage = [&](int c, int bufi) {
        const float* src = I1p + (size_t)c * CH * H1 + lane * 4;
#pragma unroll
        for (int s = 0; s < CH; ++s) {
            LDS_GLOAD16(src + (size_t)s * H1,       &Ich[bufi][s][0]);
            LDS_GLOAD16(src + (size_t)s * H1 + 256, &Ich[bufi][s][256]);
        }
    };

    stage(0, 0);

    for (int c = 0; c < NC; ++c) {
        const int buf = c & 1;
        asm volatile("s_waitcnt vmcnt(0)" ::: "memory");

        float cur[8];
#pragma unroll
        for (int j = 0; j < 8; ++j) cur[j] = Ich[buf][0][lane + 64 * j];

        for (int s = 0; s < CH; ++s) {
            float nxt[8];
            if (s + 1 < CH) {
#pragma unroll
                for (int j = 0; j < 8; ++j) nxt[j] = Ich[buf][s + 1][lane + 64 * j];
            }

            float rec[8] = {0.f,0.f,0.f,0.f,0.f,0.f,0.f,0.f};
            if (prev1) {
#pragma unroll
                for (int w = 0; w < 8; ++w) {
                    unsigned long long bits = M1[w];
                    while (bits) {
                        int p = __builtin_ctzll(bits);
                        bits &= bits - 1;
                        int i = (w << 6) + p;
                        const float* r = wrt + (size_t)i * H1 + lane;
#pragma unroll
                        for (int j = 0; j < 8; ++j) rec[j] += r[64 * j];
                    }
                }
            }

            unsigned m = 0;
#pragma unroll
            for (int j = 0; j < 8; ++j) {
                float I1v = cur[j] + rec[j];
                float v1n = fmaf(al1[j], v1[j], oml1[j] * (I1v - a1[j]));
                bool  sp  = v1n > 1.f;
                v1[j] = sp ? v1n - 1.f : v1n;
                a1[j] = fmaf(rh1[j], a1[j], ba1[j] * s1f[j]);
                s1f[j] = sp ? 1.f : 0.f;
                m |= (sp ? 1u : 0u) << j;
            }

            unsigned long long anyb = __ballot(m != 0);
            float I2[4] = {0.f, 0.f, 0.f, 0.f};
            if (anyb) {
                prev1 = true;
#pragma unroll
                for (int j = 0; j < 8; ++j) M1[j] = __ballot((m >> j) & 1);
#pragma unroll
                for (int w = 0; w < 8; ++w) {
                    unsigned long long bits = M1[w];
                    while (bits) {
                        int p = __builtin_ctzll(bits);
                        bits &= bits - 1;
                        int i = (w << 6) + p;
                        const float* r = w2t + (size_t)i * H2 + lane;
#pragma unroll
                        for (int j = 0; j < 4; ++j) I2[j] += r[64 * j];
                    }
                }
            } else {
                prev1 = false;
            }

            unsigned m2 = 0;
#pragma unroll
            for (int j = 0; j < 4; ++j) {
                float v2n = fmaf(al2[j], v2[j], oml2[j] * (I2[j] - a2[j]));
                bool  sp  = v2n > 1.f;
                v2[j] = sp ? v2n - 1.f : v2n;
                a2[j] = fmaf(rh2[j], a2[j], ba2[j] * s2f[j]);
                s2f[j] = sp ? 1.f : 0.f;
                m2 |= (sp ? 1u : 0u) << j;
            }

            unsigned long long any2 = __ballot(m2 != 0);
            float io0 = 0.f, io1 = 0.f;
            if (any2) {
#pragma unroll
                for (int w = 0; w < 4; ++w) {
                    unsigned long long bits = __ballot((m2 >> w) & 1);
                    while (bits) {
                        int p = __builtin_ctzll(bits);
                        bits &= bits - 1;
                        int i = (w << 6) + p;
                        io0 += w3t[(size_t)i * NOUT + lane];
                        if (lane < NOUT - 64) io1 += w3t[(size_t)i * NOUT + 64 + lane];
                    }
                }
            }
            vo0 = fmaf(bo0, vo0, ombo0 * io0);
            vo1 = fmaf(bo1, vo1, ombo1 * io1);
            vs0 += vo0;
            vs1 += vo1;

#pragma unroll
            for (int j = 0; j < 8; ++j) cur[j] = nxt[j];
        }

        if (c + 1 < NC) stage(c + 1, buf ^ 1);
    }

    out[b * NOUT + lane] = vs0 * (1.f / (float)T_);
    if (lane < NOUT - 64) out[b * NOUT + 64 + lane] = vs1 * (1.f / (float)T_);
}

// ---------------- launch ----------------
extern "C" void kernel_launch(void* const* d_in, const int* in_sizes, int n_in,
                              void* d_out, int out_size, void* d_ws, size_t ws_size,
                              hipStream_t stream) {
    const float* x      = (const float*)d_in[0];   // [B][T][NIN]
    const float* w1     = (const float*)d_in[1];   // [H1][NIN]
    const float* w_rec  = (const float*)d_in[2];   // [H1][H1]
    const float* w2     = (const float*)d_in[3];   // [H2][H1]
    const float* w3     = (const float*)d_in[4];   // [NOUT][H2]
    const float* alpha1 = (const float*)d_in[5];
    const float* rho1   = (const float*)d_in[6];
    const float* beta_a1= (const float*)d_in[7];
    const float* alpha2 = (const float*)d_in[8];
    const float* rho2   = (const float*)d_in[9];
    const float* beta_a2= (const float*)d_in[10];
    const float* beta_out=(const float*)d_in[11];
    float* out = (float*)d_out;

    const int M = B_ * T_;                         // 19200

    size_t off = 0;
    auto take = [&](size_t bytes) {
        void* p = (char*)d_ws + off;
        off += (bytes + 255) & ~(size_t)255;
        return p;
    };
    float* I1ff = (float*)take((size_t)M * H1 * 4);            // 39.3 MB
    float* wrt  = (float*)take((size_t)H1 * H1 * 4);
    float* w2t  = (float*)take((size_t)H1 * H2 * 4);
    float* w3t  = (float*)take((size_t)H2 * NOUT * 4);
    unsigned short* xb  = (unsigned short*)take((size_t)M * KP * 2);   // 90.9 MB
    unsigned short* w1b = (unsigned short*)take((size_t)H1 * KP * 2);  // 2.4 MB

    transpose_k<<<(H1 * H1 + 255) / 256, 256, 0, stream>>>(w_rec, wrt, H1, H1);
    transpose_k<<<(H2 * H1 + 255) / 256, 256, 0, stream>>>(w2, w2t, H2, H1);
    transpose_k<<<(NOUT * H2 + 255) / 256, 256, 0, stream>>>(w3, w3t, NOUT, H2);

    // X and W -> bf16 (vectorized, HBM/L3-bound)
    int nx = M * (KP / 8);
    cvt_pad_bf16<<<(nx + 255) / 256, 256, 0, stream>>>(x, xb, M, NIN, KP);
    int nw = H1 * (KP / 8);
    cvt_pad_bf16<<<(nw + 255) / 256, 256, 0, stream>>>(w1, w1b, H1, NIN, KP);

    // 128x256-tile bf16 GEMM: 300 blocks x 512 threads
    gemm_bf16<<<300, 512, 0, stream>>>(xb, w1b, I1ff);

    snn_scan_wave<<<B_, 64, 0, stream>>>(I1ff, wrt, w2t, w3t,
                                         alpha1, rho1, beta_a1,
                                         alpha2, rho2, beta_a2,
                                         beta_out, out);
}